// Round 1
// baseline (304.425 us; speedup 1.0000x reference)
//
#include <hip/hip_runtime.h>
#include <hip/hip_bf16.h>

#define T_DIM 4096
#define B_DIM 4
#define H_DIM 256   // NHID == QDIM == 256

typedef unsigned short u16;
typedef __attribute__((ext_vector_type(8))) short short8;
typedef __attribute__((ext_vector_type(8))) __bf16 bf16x8;
typedef __attribute__((ext_vector_type(4))) float f32x4;

static __device__ __forceinline__ u16 f2bf(float f) {
    union { float f; unsigned int u; } v; v.f = f;
    unsigned int u = v.u;
    u += 0x7FFFu + ((u >> 16) & 1u);   // RNE
    return (u16)(u >> 16);
}

static __device__ __forceinline__ f32x4 mfma16(short8 a, short8 b, f32x4 c) {
    return __builtin_amdgcn_mfma_f32_16x16x32_bf16(
        __builtin_bit_cast(bf16x8, a), __builtin_bit_cast(bf16x8, b), c, 0, 0, 0);
}

// ---------------------------------------------------------------------------
// Kernel 0: transpose + convert the three 256x256 fp32 weights to bf16 W^T[n][k]
// ---------------------------------------------------------------------------
__global__ __launch_bounds__(256) void wtrans_kernel(
    const float* __restrict__ Wq, const float* __restrict__ Wk,
    const float* __restrict__ Wv, u16* __restrict__ wT) {
    int idx = blockIdx.x * 256 + threadIdx.x;   // 0 .. 3*65536-1
    int w   = idx >> 16;
    int rem = idx & 65535;
    int k   = rem >> 8;
    int n   = rem & 255;
    const float* W = (w == 0) ? Wq : (w == 1) ? Wk : Wv;
    wT[w * 65536 + n * 256 + k] = f2bf(W[k * 256 + n]);
}

// ---------------------------------------------------------------------------
// Kernel 1: projection GEMM.  X[16384][256] fp32 @ W[256][256] -> bf16.
//   w_sel 0 -> q_ws[b][t][d], 1 -> k_ws[b][t][d], 2 -> vT_ws[b][d][t]
// Block: 256 thr (4 waves), 64 rows x 256 cols. A-frags direct from global X,
// B-frags direct from bf16 W^T (L1/L2 resident).
// ---------------------------------------------------------------------------
__global__ __launch_bounds__(256, 2) void proj_kernel(
    const float* __restrict__ X, const u16* __restrict__ wT,
    u16* __restrict__ q_ws, u16* __restrict__ k_ws, u16* __restrict__ vT_ws) {
    const int w_sel = blockIdx.y;
    const int r0    = blockIdx.x * 64;
    const int wid   = threadIdx.x >> 6, lane = threadIdx.x & 63;
    const int lr    = lane & 15, lg = lane >> 4;

    const float* xrow  = X + (size_t)(r0 + 16 * wid + lr) * 256 + lg * 8;
    const u16*   wbase = wT + w_sel * 65536 + lr * 256 + lg * 8;

    f32x4 acc[16];
#pragma unroll
    for (int i = 0; i < 16; ++i) acc[i] = (f32x4){0.f, 0.f, 0.f, 0.f};

#pragma unroll
    for (int kc = 0; kc < 8; ++kc) {
        f32x4 xa = *(const f32x4*)(xrow + kc * 32);
        f32x4 xb = *(const f32x4*)(xrow + kc * 32 + 4);
        union { u16 u[8]; short8 v; } af;
#pragma unroll
        for (int e = 0; e < 4; ++e) { af.u[e] = f2bf(xa[e]); af.u[4 + e] = f2bf(xb[e]); }
#pragma unroll
        for (int nf = 0; nf < 16; ++nf) {
            short8 bfv = *(const short8*)(wbase + nf * 4096 + kc * 32);
            acc[nf] = mfma16(af.v, bfv, acc[nf]);
        }
    }
#pragma unroll
    for (int nf = 0; nf < 16; ++nf) {
#pragma unroll
        for (int r = 0; r < 4; ++r) {
            int rg = r0 + 16 * wid + 4 * lg + r;
            int t  = rg >> 2, bb = rg & 3;
            int d  = 16 * nf + lr;
            u16 val = f2bf(acc[nf][r]);
            if (w_sel == 0)      q_ws[((size_t)bb * T_DIM + t) * 256 + d] = val;
            else if (w_sel == 1) k_ws[((size_t)bb * T_DIM + t) * 256 + d] = val;
            else                 vT_ws[((size_t)bb * 256 + d) * T_DIM + t] = val;
        }
    }
}

// ---------------------------------------------------------------------------
// Kernel 2: fused causal attention.  One block = (b, 32-row query tile).
// Two sweeps over 64-wide K tiles: (1) row sums of exp(S), (2) write
// attn = exp(S)/l (fp32, nontemporal), P->LDS (bf16), PV accumulate, then
// write O and zero-fill the upper triangle.
// ---------------------------------------------------------------------------
__global__ __launch_bounds__(256, 2) void attn_kernel(
    const u16* __restrict__ q_ws, const u16* __restrict__ k_ws,
    const u16* __restrict__ vT_ws, float* __restrict__ out) {
    __shared__ float l_sm[32];
    __shared__ __align__(16) u16 P_sm[32 * 72];   // padded stride 72

    // block -> (b, i_tile): one b per XCD (blk&7 -> xcd), snake for balance
    const int blk = blockIdx.x;
    const int xcd = blk & 7, t = blk >> 3;
    const int b = xcd >> 1, par = xcd & 1;
    const int m = (t < 32) ? t : 95 - t;       // snake: CU gets m=c and 63-c
    const int i_tile = 2 * m + par;            // 0..127
    const int i0 = i_tile * 32;

    const int wid = threadIdx.x >> 6, lane = threadIdx.x & 63;
    const int lr = lane & 15, lg = lane >> 4;

    float* attnO = out + (size_t)T_DIM * B_DIM * 256 + (size_t)b * T_DIM * T_DIM;

    // Q fragments held in registers for the whole kernel
    short8 q8[2][8];
    {
        const u16* qbase = q_ws + ((size_t)b * T_DIM + i0 + lr) * 256 + lg * 8;
#pragma unroll
        for (int mf = 0; mf < 2; ++mf)
#pragma unroll
            for (int kc = 0; kc < 8; ++kc)
                q8[mf][kc] = *(const short8*)(qbase + mf * 16 * 256 + kc * 32);
    }
    if (threadIdx.x < 32) l_sm[threadIdx.x] = 0.f;
    __syncthreads();

    const int numJT = (i0 + 31) / 64 + 1;
    const u16* kbase = k_ws + (size_t)b * T_DIM * 256 + (16 * wid + lr) * 256 + lg * 8;

    // ---- sweep 1: row sums of exp(S) ----
    float rs[2][4] = {{0.f,0.f,0.f,0.f},{0.f,0.f,0.f,0.f}};
    for (int jt = 0; jt < numJT; ++jt) {
        const int j0 = jt * 64;
        f32x4 a0 = {0.f,0.f,0.f,0.f}, a1 = {0.f,0.f,0.f,0.f};
        const u16* kp = kbase + (size_t)j0 * 256;
#pragma unroll
        for (int kc = 0; kc < 8; ++kc) {
            short8 kf = *(const short8*)(kp + kc * 32);
            a0 = mfma16(q8[0][kc], kf, a0);
            a1 = mfma16(q8[1][kc], kf, a1);
        }
        const int j = j0 + 16 * wid + lr;
#pragma unroll
        for (int r = 0; r < 4; ++r) {
            int ia = i0 + 4 * lg + r;
            rs[0][r] += (j <= ia)      ? __expf(a0[r] * 0.0625f) : 0.f;
            rs[1][r] += (j <= ia + 16) ? __expf(a1[r] * 0.0625f) : 0.f;
        }
    }
#pragma unroll
    for (int mf = 0; mf < 2; ++mf)
#pragma unroll
        for (int r = 0; r < 4; ++r) {
            float v = rs[mf][r];
            for (int s = 1; s < 16; s <<= 1) v += __shfl_xor(v, s, 64);
            if (lr == 0) atomicAdd(&l_sm[16 * mf + 4 * lg + r], v);
        }
    __syncthreads();
    if (threadIdx.x < 32) l_sm[threadIdx.x] = 1.0f / l_sm[threadIdx.x];
    __syncthreads();
    float inv8[2][4];
#pragma unroll
    for (int mf = 0; mf < 2; ++mf)
#pragma unroll
        for (int r = 0; r < 4; ++r) inv8[mf][r] = l_sm[16 * mf + 4 * lg + r];

    // ---- sweep 2: attn write + PV ----
    f32x4 oacc[2][4];
#pragma unroll
    for (int mf = 0; mf < 2; ++mf)
#pragma unroll
        for (int nf = 0; nf < 4; ++nf) oacc[mf][nf] = (f32x4){0.f,0.f,0.f,0.f};

    const u16* vbase = vT_ws + (size_t)b * 256 * T_DIM + (size_t)(64 * wid + lr) * T_DIM + lg * 8;

    for (int jt = 0; jt < numJT; ++jt) {
        const int j0 = jt * 64;
        f32x4 a0 = {0.f,0.f,0.f,0.f}, a1 = {0.f,0.f,0.f,0.f};
        const u16* kp = kbase + (size_t)j0 * 256;
#pragma unroll
        for (int kc = 0; kc < 8; ++kc) {
            short8 kf = *(const short8*)(kp + kc * 32);
            a0 = mfma16(q8[0][kc], kf, a0);
            a1 = mfma16(q8[1][kc], kf, a1);
        }
        const int j = j0 + 16 * wid + lr;
#pragma unroll
        for (int r = 0; r < 4; ++r) {
            {
                int ig = i0 + 4 * lg + r;
                float p = (j <= ig) ? __expf(a0[r] * 0.0625f) * inv8[0][r] : 0.f;
                __builtin_nontemporal_store(p, attnO + (size_t)ig * T_DIM + j);
                P_sm[(4 * lg + r) * 72 + 16 * wid + lr] = f2bf(p);
            }
            {
                int ig = i0 + 16 + 4 * lg + r;
                float p = (j <= ig) ? __expf(a1[r] * 0.0625f) * inv8[1][r] : 0.f;
                __builtin_nontemporal_store(p, attnO + (size_t)ig * T_DIM + j);
                P_sm[(16 + 4 * lg + r) * 72 + 16 * wid + lr] = f2bf(p);
            }
        }
        __syncthreads();
#pragma unroll
        for (int ks = 0; ks < 2; ++ks) {
            short8 pa0 = *(const short8*)(P_sm + lr * 72 + ks * 32 + lg * 8);
            short8 pa1 = *(const short8*)(P_sm + (16 + lr) * 72 + ks * 32 + lg * 8);
#pragma unroll
            for (int nf = 0; nf < 4; ++nf) {
                short8 vf = *(const short8*)(vbase + (size_t)nf * 16 * T_DIM + j0 + ks * 32);
                oacc[0][nf] = mfma16(pa0, vf, oacc[0][nf]);
                oacc[1][nf] = mfma16(pa1, vf, oacc[1][nf]);
            }
        }
        __syncthreads();
    }

    // write O -> results[t][b][d]
#pragma unroll
    for (int mf = 0; mf < 2; ++mf)
#pragma unroll
        for (int nf = 0; nf < 4; ++nf)
#pragma unroll
            for (int r = 0; r < 4; ++r) {
                int ig = i0 + 16 * mf + 4 * lg + r;
                int d  = 64 * wid + 16 * nf + lr;
                __builtin_nontemporal_store(oacc[mf][nf][r],
                    out + ((size_t)ig * B_DIM + b) * 256 + d);
            }

    // zero-fill strict upper triangle beyond the computed tiles
    const int z0 = numJT * 64;
    if (z0 < T_DIM) {
        const int perRow = (T_DIM - z0) >> 2;
        for (int rr = 0; rr < 32; ++rr) {
            f32x4* rowp = (f32x4*)(attnO + (size_t)(i0 + rr) * T_DIM + z0);
            for (int c = threadIdx.x; c < perRow; c += 256) {
                f32x4 z = {0.f, 0.f, 0.f, 0.f};
                __builtin_nontemporal_store(z, rowp + c);
            }
        }
    }
}

// ---------------------------------------------------------------------------
extern "C" void kernel_launch(void* const* d_in, const int* in_sizes, int n_in,
                              void* d_out, int out_size, void* d_ws, size_t ws_size,
                              hipStream_t stream) {
    (void)in_sizes; (void)n_in; (void)out_size; (void)ws_size;
    const float* X  = (const float*)d_in[0];
    const float* Wq = (const float*)d_in[1];
    const float* Wk = (const float*)d_in[2];
    const float* Wv = (const float*)d_in[3];
    float* out = (float*)d_out;

    char* ws = (char*)d_ws;
    u16* q_ws  = (u16*)(ws);                                  // 8 MB
    u16* k_ws  = (u16*)(ws + (size_t)8  * 1024 * 1024);       // 8 MB
    u16* vT_ws = (u16*)(ws + (size_t)16 * 1024 * 1024);       // 8 MB
    u16* wT    = (u16*)(ws + (size_t)24 * 1024 * 1024);       // 384 KB

    wtrans_kernel<<<dim3(768), dim3(256), 0, stream>>>(Wq, Wk, Wv, wT);
    proj_kernel<<<dim3(256, 3), dim3(256), 0, stream>>>(X, wT, q_ws, k_ws, vT_ws);
    attn_kernel<<<dim3(512), dim3(256), 0, stream>>>(q_ws, k_ws, vT_ws, out);
}